// Round 5
// baseline (571.573 us; speedup 1.0000x reference)
//
#include <hip/hip_runtime.h>
#include <hip/hip_bf16.h>

// FourierAttention: x[4,2048,1024] f32; single-head attention over d_model=1024.
// Algebra: out = P·(x·Wvo^T) + (Wo·bv + bo), Wvo = Wo·Wv (softmax rows sum to 1).
//
// GEMM core (R5): barrier-free, LDS-free. Both operands K-contiguous; the
// 16x16x32 bf16 MFMA fragment (lane m=lane&15, k=(lane>>4)*8+j) is a 16B
// contiguous global load per lane -> fragments load straight to VGPRs.
// 2-deep register pipeline, compiler emits fine-grained s_waitcnt vmcnt(N)
// (no __syncthreads drain anywhere). 128x128 block tile, 4 waves, 64x64/wave.
//
// Epilogues: scores GEMM runs role-swapped (A=K, B=Q) so lanes hold 4
// consecutive k -> packed 8B stores into P[q][k] (full line coverage, no
// write amplification). V^T scatter packed to 8B for the same reason.

#define BK 32

typedef __attribute__((ext_vector_type(8))) short bf16x8;
typedef __attribute__((ext_vector_type(4))) float f32x4;
struct alignas(8) s16x4 { short a, b, c, d; };

__device__ __forceinline__ short bfpack(float v) {
  return __builtin_bit_cast(short, __float2bfloat16(v));
}

// 64x64 per-wave register-fragment GEMM: C = A[rows wr..][K] * B[rows wc..][K]^T
__device__ __forceinline__ void gemm_core_reg(
    const __hip_bfloat16* __restrict__ A, const __hip_bfloat16* __restrict__ B,
    long rowBase, long colBase, int K, int wr, int wc, int lr, int q,
    f32x4 acc[4][4])
{
  const __hip_bfloat16* pa = A + (rowBase + wr + lr) * (long)K + q * 8;
  const __hip_bfloat16* pb = B + (colBase + wc + lr) * (long)K + q * 8;
  const long rs = 16 * (long)K;

  bf16x8 a0[4], b0[4];
  #pragma unroll
  for (int i = 0; i < 4; ++i) a0[i] = *(const bf16x8*)(pa + i * rs);
  #pragma unroll
  for (int i = 0; i < 4; ++i) b0[i] = *(const bf16x8*)(pb + i * rs);

  for (int k0 = 0; k0 < K; k0 += BK) {
    bf16x8 a1[4], b1[4];
    const bool more = (k0 + BK < K);
    if (more) {
      #pragma unroll
      for (int i = 0; i < 4; ++i) a1[i] = *(const bf16x8*)(pa + (k0 + BK) + i * rs);
      #pragma unroll
      for (int i = 0; i < 4; ++i) b1[i] = *(const bf16x8*)(pb + (k0 + BK) + i * rs);
    }
    #pragma unroll
    for (int mi = 0; mi < 4; ++mi)
      #pragma unroll
      for (int ni = 0; ni < 4; ++ni)
        acc[mi][ni] = __builtin_amdgcn_mfma_f32_16x16x32_bf16(
            a0[mi], b0[ni], acc[mi][ni], 0, 0, 0);
    if (more) {
      #pragma unroll
      for (int i = 0; i < 4; ++i) { a0[i] = a1[i]; b0[i] = b1[i]; }
    }
  }
}

// ---------------- generic GEMM ----------------
// mode: 0 = bf16 row-major (scalar stores), 2 = f32 row-major,
//       3 = bf16 transposed-packed: store C^T, i.e. Cb[col*ldC + row], 8B packed.
__global__ __launch_bounds__(256) void gemm_bt(
    const __hip_bfloat16* __restrict__ A,
    const __hip_bfloat16* __restrict__ B,
    void* __restrict__ Cv,
    const float* __restrict__ bias,
    int K, int ldC,
    long sA, long sB, long sC,
    float scale, int mode)
{
  const long z = blockIdx.z;
  const int tid  = threadIdx.x;
  const int lane = tid & 63;
  const int wid  = tid >> 6;
  const int wr   = (wid >> 1) * 64;
  const int wc   = (wid & 1) * 64;
  const int lr   = lane & 15;
  const int q    = lane >> 4;

  const long rowBase = (long)blockIdx.x * 128;
  const long colBase = (long)blockIdx.y * 128;

  f32x4 acc[4][4] = {};
  gemm_core_reg(A + z * sA, B + z * sB, rowBase, colBase, K, wr, wc, lr, q, acc);

  if (mode == 3) {
    // C^T packed: lane holds col (lr) fixed, 4 consecutive rows -> 8B store.
    __hip_bfloat16* Cb = (__hip_bfloat16*)Cv + z * sC;
    #pragma unroll
    for (int ni = 0; ni < 4; ++ni) {
      long col = colBase + wc + ni * 16 + lr;
      #pragma unroll
      for (int mi = 0; mi < 4; ++mi) {
        long row = rowBase + wr + mi * 16 + q * 4;
        s16x4 pk = { bfpack(acc[mi][ni][0] * scale), bfpack(acc[mi][ni][1] * scale),
                     bfpack(acc[mi][ni][2] * scale), bfpack(acc[mi][ni][3] * scale) };
        *(s16x4*)(Cb + col * (long)ldC + row) = pk;
      }
    }
    return;
  }

  #pragma unroll
  for (int ni = 0; ni < 4; ++ni) {
    long col = colBase + wc + ni * 16 + lr;
    float bv = bias ? bias[col] : 0.0f;
    #pragma unroll
    for (int mi = 0; mi < 4; ++mi) {
      #pragma unroll
      for (int i = 0; i < 4; ++i) {
        long row = rowBase + wr + mi * 16 + q * 4 + i;
        float v = acc[mi][ni][i] * scale + bv;
        if (mode == 0)
          ((__hip_bfloat16*)Cv)[z * sC + row * (long)ldC + col] = __float2bfloat16(v);
        else
          ((float*)Cv)[z * sC + row * (long)ldC + col] = v;
      }
    }
  }
}

// ---------------- fused QKV projection (V-slot carries Wvo) ----------------
// A = xb[8192,1024], B = Wqkvb[3072,1024] (Wq | Wk | Wvo). Col group (block-
// uniform): 0 -> Q[8192,1024] (+bq), 1 -> K[8192,1024] (+bk),
// 2 -> VWo^T[B=4][D=1024][S=2048] packed 8B stores, no bias (folded into bfinal).
__global__ __launch_bounds__(256) void gemm_qkv(
    const __hip_bfloat16* __restrict__ A,
    const __hip_bfloat16* __restrict__ B,
    __hip_bfloat16* __restrict__ Q,
    __hip_bfloat16* __restrict__ Kd,
    __hip_bfloat16* __restrict__ Vt,
    const float* __restrict__ bq,
    const float* __restrict__ bk)
{
  const int tid  = threadIdx.x;
  const int lane = tid & 63;
  const int wid  = tid >> 6;
  const int wr   = (wid >> 1) * 64;
  const int wc   = (wid & 1) * 64;
  const int lr   = lane & 15;
  const int q    = lane >> 4;

  const long rowBase = (long)blockIdx.x * 128;
  const long colBase = (long)blockIdx.y * 128;

  f32x4 acc[4][4] = {};
  gemm_core_reg(A, B, rowBase, colBase, 1024, wr, wc, lr, q, acc);

  const int cg = (int)(colBase >> 10);  // 0=Q, 1=K, 2=VWo (block-uniform)

  if (cg == 2) {
    #pragma unroll
    for (int ni = 0; ni < 4; ++ni) {
      long colL = (colBase + wc + ni * 16 + lr) & 1023;
      #pragma unroll
      for (int mi = 0; mi < 4; ++mi) {
        long row0 = rowBase + wr + mi * 16 + q * 4;   // rows row0..row0+3, same batch
        long b = row0 >> 11, s = row0 & 2047;
        s16x4 pk = { bfpack(acc[mi][ni][0]), bfpack(acc[mi][ni][1]),
                     bfpack(acc[mi][ni][2]), bfpack(acc[mi][ni][3]) };
        *(s16x4*)(Vt + b * (1024L * 2048L) + colL * 2048L + s) = pk;
      }
    }
    return;
  }

  __hip_bfloat16* Dst = (cg == 0) ? Q : Kd;
  const float* bias = (cg == 0) ? bq : bk;
  #pragma unroll
  for (int ni = 0; ni < 4; ++ni) {
    long colL = (colBase + wc + ni * 16 + lr) & 1023;
    float bvv = bias[colL];
    #pragma unroll
    for (int mi = 0; mi < 4; ++mi) {
      #pragma unroll
      for (int i = 0; i < 4; ++i) {
        long row = rowBase + wr + mi * 16 + q * 4 + i;
        Dst[row * 1024 + colL] = __float2bfloat16(acc[mi][ni][i] + bvv);
      }
    }
  }
}

// f32 -> bf16 conversion, 8 elems/thread.
__global__ __launch_bounds__(256) void cvt_f32_bf16(
    const float* __restrict__ in, __hip_bfloat16* __restrict__ out)
{
  long i = ((long)blockIdx.x * 256 + threadIdx.x) * 8;
  float4 a = *(const float4*)(in + i);
  float4 b = *(const float4*)(in + i + 4);
  bf16x8 o;
  o[0] = bfpack(a.x); o[1] = bfpack(a.y); o[2] = bfpack(a.z); o[3] = bfpack(a.w);
  o[4] = bfpack(b.x); o[5] = bfpack(b.y); o[6] = bfpack(b.z); o[7] = bfpack(b.w);
  *(bf16x8*)(out + i) = o;
}

// Transpose-convert: in f32 [1024][1024] -> out bf16 transposed. 64x64 LDS tiles.
__global__ __launch_bounds__(256) void cvt_t_f32_bf16(
    const float* __restrict__ in, __hip_bfloat16* __restrict__ out)
{
  __shared__ __hip_bfloat16 t[64][65];
  const int tid = threadIdx.x;
  const long rb = (long)blockIdx.y * 64;
  const long cb = (long)blockIdx.x * 64;
  const int r0 = tid >> 4;
  const int c0 = (tid & 15) * 4;
  #pragma unroll
  for (int p = 0; p < 4; ++p) {
    int r = r0 + p * 16;
    float4 v = *(const float4*)(in + (rb + r) * 1024 + cb + c0);
    t[c0 + 0][r] = __float2bfloat16(v.x);
    t[c0 + 1][r] = __float2bfloat16(v.y);
    t[c0 + 2][r] = __float2bfloat16(v.z);
    t[c0 + 3][r] = __float2bfloat16(v.w);
  }
  __syncthreads();
  #pragma unroll
  for (int p = 0; p < 4; ++p) {
    int r = r0 + p * 16;
    __hip_bfloat16* o = out + (cb + r) * 1024 + rb + c0;
    o[0] = t[r][c0 + 0]; o[1] = t[r][c0 + 1];
    o[2] = t[r][c0 + 2]; o[3] = t[r][c0 + 3];
  }
}

// bfinal[e] = dot(Wo[e,:], bv) + bo[e]  (f32)
__global__ __launch_bounds__(256) void bias_vo(
    const float* __restrict__ Wo, const float* __restrict__ bv,
    const float* __restrict__ bo, float* __restrict__ bfinal)
{
  int e = blockIdx.x * 4 + (threadIdx.x >> 6);
  int lane = threadIdx.x & 63;
  const float* row = Wo + (long)e * 1024;
  float s = 0.0f;
  #pragma unroll
  for (int p = 0; p < 4; ++p) {
    float4 w = *(const float4*)(row + p * 256 + lane * 4);
    float4 b = *(const float4*)(bv + p * 256 + lane * 4);
    s += w.x * b.x + w.y * b.y + w.z * b.z + w.w * b.w;
  }
  #pragma unroll
  for (int o = 32; o; o >>= 1) s += __shfl_xor(s, o);
  if (lane == 0) bfinal[e] = s + bo[e];
}

// In-place row softmax over 2048 bf16 elements. One 256-thread block per row.
__global__ __launch_bounds__(256) void softmax_rows(__hip_bfloat16* __restrict__ P)
{
  const int tid  = threadIdx.x;
  const int lane = tid & 63;
  const int wid  = tid >> 6;
  __hip_bfloat16* p = P + (long)blockIdx.x * 2048 + tid * 8;

  bf16x8 v = *(const bf16x8*)p;
  float x[8];
  #pragma unroll
  for (int i = 0; i < 8; ++i)
    x[i] = __uint_as_float(((unsigned)(unsigned short)v[i]) << 16);

  float m = x[0];
  #pragma unroll
  for (int i = 1; i < 8; ++i) m = fmaxf(m, x[i]);
  #pragma unroll
  for (int o = 32; o; o >>= 1) m = fmaxf(m, __shfl_xor(m, o));

  __shared__ float rmax[4], rsum[4];
  if (lane == 0) rmax[wid] = m;
  __syncthreads();
  m = fmaxf(fmaxf(rmax[0], rmax[1]), fmaxf(rmax[2], rmax[3]));

  float e[8], s = 0.0f;
  #pragma unroll
  for (int i = 0; i < 8; ++i) { e[i] = __expf(x[i] - m); s += e[i]; }
  #pragma unroll
  for (int o = 32; o; o >>= 1) s += __shfl_xor(s, o);
  if (lane == 0) rsum[wid] = s;
  __syncthreads();
  s = (rsum[0] + rsum[1]) + (rsum[2] + rsum[3]);

  float inv = 1.0f / s;
  bf16x8 ov;
  #pragma unroll
  for (int i = 0; i < 8; ++i) ov[i] = bfpack(e[i] * inv);
  *(bf16x8*)p = ov;
}

extern "C" void kernel_launch(void* const* d_in, const int* in_sizes, int n_in,
                              void* d_out, int out_size, void* d_ws, size_t ws_size,
                              hipStream_t stream) {
  const float* x  = (const float*)d_in[0];
  const float* Wq = (const float*)d_in[1];
  const float* bq = (const float*)d_in[2];
  const float* Wk = (const float*)d_in[3];
  const float* bk = (const float*)d_in[4];
  const float* Wv = (const float*)d_in[5];
  const float* bv = (const float*)d_in[6];
  const float* Wo = (const float*)d_in[7];
  const float* bo = (const float*)d_in[8];
  float* out = (float*)d_out;

  const long B = 4, S = 2048, D = 1024;
  char* ws = (char*)d_ws;
  __hip_bfloat16* xb    = (__hip_bfloat16*)ws; ws += B * S * D * 2;  // 16.8 MB
  __hip_bfloat16* Wqkvb = (__hip_bfloat16*)ws; ws += 3 * D * D * 2;  //  6.3 MB (Wq|Wk|Wvo)
  __hip_bfloat16* Wob   = (__hip_bfloat16*)ws; ws += D * D * 2;      //  2.1 MB
  __hip_bfloat16* Q     = (__hip_bfloat16*)ws; ws += B * S * D * 2;  // 16.8 MB
  __hip_bfloat16* Km    = (__hip_bfloat16*)ws; ws += B * S * D * 2;  // 16.8 MB
  __hip_bfloat16* VWot  = (__hip_bfloat16*)ws; ws += B * D * S * 2;  // 16.8 MB [B][D][S]
  __hip_bfloat16* P     = (__hip_bfloat16*)ws; ws += B * S * S * 2;  // 33.5 MB
  __hip_bfloat16* Wvtb   = Q;            // Wv^T bf16, dead before gemm_qkv writes Q
  float*          bfinal = (float*)Wob;  // overwrites Wob AFTER the Wvo GEMM reads it

  dim3 blk(256);
  // converts
  cvt_f32_bf16<<<dim3(4096), blk, 0, stream>>>(x,  xb);
  cvt_f32_bf16<<<dim3(512),  blk, 0, stream>>>(Wq, Wqkvb);
  cvt_f32_bf16<<<dim3(512),  blk, 0, stream>>>(Wk, Wqkvb + D * D);
  cvt_f32_bf16<<<dim3(512),  blk, 0, stream>>>(Wo, Wob);
  cvt_t_f32_bf16<<<dim3(16, 16), blk, 0, stream>>>(Wv, Wvtb);

  // Wvo = Wo · Wv (via Wv^T) -> QKV weight slot 2
  gemm_bt<<<dim3(8, 8, 1), blk, 0, stream>>>(Wob, Wvtb, Wqkvb + 2 * D * D,
                                             nullptr, 1024, 1024, 0, 0, 0, 1.0f, 0);
  // bfinal = Wo·bv + bo (overwrites Wob region, safe after Wvo GEMM)
  bias_vo<<<dim3(256), blk, 0, stream>>>(Wo, bv, bo, bfinal);

  // fused QKV projection: M=8192, N=3072, K=1024 -> Q, K, VWo^T
  gemm_qkv<<<dim3(64, 24, 1), blk, 0, stream>>>(xb, Wqkvb, Q, Km, VWot, bq, bk);
  // scores^T orientation: A=K, B=Q, mode 3 stores P[q][k] with packed 8B rows.
  gemm_bt<<<dim3(16, 16, 4), blk, 0, stream>>>(Km, Q, P, nullptr, 1024, 2048,
                                               S * D, S * D, S * S, 0.125f, 3);
  // softmax over each of 4*2048 rows
  softmax_rows<<<dim3(8192), blk, 0, stream>>>(P);
  // out = P · VWo + bfinal (f32): M=2048, N=1024, K=2048, batched
  gemm_bt<<<dim3(16, 8, 4), blk, 0, stream>>>(P, VWot, out, bfinal, 2048, 1024,
                                              S * S, D * S, S * D, 1.0f, 2);
}

// Round 6
// 365.388 us; speedup vs baseline: 1.5643x; 1.5643x over previous
//
#include <hip/hip_runtime.h>
#include <hip/hip_bf16.h>

// FourierAttention: x[4,2048,1024] f32; single-head attention over d_model=1024.
// Algebra: out = P·(x·Wvo^T) + (Wo·bv + bo), Wvo = Wo·Wv (softmax rows sum to 1).
//
// GEMM core (R6): producer-consumer wave specialization. Block = 320 threads:
// wave 4 = producer streaming 128x32 A/B K-tiles into a 3-slot LDS ring via
// global_load_lds (16 insts/tile, 1KB each), confirming slot k-1 with a private
// s_waitcnt vmcnt(<=16) — never a block-wide vmcnt(0) drain. Waves 0-3 =
// consumers (64x64 subtile each), gated on a monotonic slots_ready LDS counter
// (read pipelined one iter early -> steady-state poll cost ~0). NO __syncthreads
// in the K-loop. Ring reuse guarded by per-slot done counters (1 atomicAdd per
// consumer wave per iter).

#define BK 32
#define NSLOT 3
#define SLOT_E (128 * BK)   // 4096 elems = 8 KB per matrix per slot

typedef __attribute__((ext_vector_type(8))) short bf16x8;
typedef __attribute__((ext_vector_type(4))) float f32x4;
struct alignas(8) s16x4 { short a, b, c, d; };

__device__ __forceinline__ short bfpack(float v) {
  return __builtin_bit_cast(short, __float2bfloat16(v));
}

// Producer wave: stream K-tiles into the LDS ring; signal via slots_ready.
__device__ __forceinline__ void producer_loop(
    const __hip_bfloat16* __restrict__ Ab, const __hip_bfloat16* __restrict__ Bb,
    __hip_bfloat16 (*As)[SLOT_E], __hip_bfloat16 (*Bs)[SLOT_E],
    volatile int* slots_ready, volatile int* done,
    long rowBase, long colBase, int K, int lane)
{
  const int NT = K / BK;
  const int rowOff = lane >> 2;        // 0..15
  const int cq = (lane & 3) * 8;       // element offset of this lane's 16B chunk
  for (int k = 0; k < NT; ++k) {
    const int slot = k % NSLOT;
    if (k >= NSLOT) {                  // wait until all 4 consumers released slot
      while (done[slot] < 4) __builtin_amdgcn_s_sleep(1);
      if (lane == 0) done[slot] = 0;
    }
    const int k0 = k * BK;
    #pragma unroll
    for (int i = 0; i < 8; ++i) {      // 8 insts A + 8 insts B, 1KB each
      const int row = i * 16 + rowOff;
      const __hip_bfloat16* ga = Ab + (rowBase + row) * (long)K + k0 + cq;
      __builtin_amdgcn_global_load_lds(
          (const __attribute__((address_space(1))) void*)ga,
          (__attribute__((address_space(3))) void*)(&As[slot][i * 512] + lane * 8),
          16, 0, 0);
      const __hip_bfloat16* gb = Bb + (colBase + row) * (long)K + k0 + cq;
      __builtin_amdgcn_global_load_lds(
          (const __attribute__((address_space(1))) void*)gb,
          (__attribute__((address_space(3))) void*)(&Bs[slot][i * 512] + lane * 8),
          16, 0, 0);
    }
    if (k >= 1) {
      // vmcnt<=16: the 16 loads of tile k-1 have landed (in-order retire);
      // tile k's 16 remain in flight. lgkm=15/exp=7 = no wait.
      __builtin_amdgcn_s_waitcnt(0x4F70);
      __asm__ volatile("" ::: "memory");
      if (lane == 0) *slots_ready = k;   // slots 0..k-1 consumable
    }
  }
  __builtin_amdgcn_s_waitcnt(0x0F70);    // vmcnt(0): last tile landed
  __asm__ volatile("" ::: "memory");
  if (lane == 0) *slots_ready = NT;
}

// Consumer wave: 64x64 subtile via 16x16x32 MFMA from the ring.
__device__ __forceinline__ void consumer_loop(
    __hip_bfloat16 (*As)[SLOT_E], __hip_bfloat16 (*Bs)[SLOT_E],
    volatile int* slots_ready, int* done,
    int K, int wr, int wc, int lr, int q, int lane, f32x4 acc[4][4])
{
  const int NT = K / BK;
  int rv = 0;
  for (int j = 0; j < NT; ++j) {
    const int slot = j % NSLOT;
    while (rv <= j) {                   // steady state: rv already >= j+1
      rv = *slots_ready;
      if (rv <= j) __builtin_amdgcn_s_sleep(1);
    }
    __asm__ volatile("" ::: "memory");  // frag reads stay below the gate
    const __hip_bfloat16* Ac = As[slot];
    const __hip_bfloat16* Bc = Bs[slot];
    bf16x8 af[4], bfr[4];
    #pragma unroll
    for (int mi = 0; mi < 4; ++mi)
      af[mi] = *(const bf16x8*)(Ac + (wr + mi * 16 + lr) * BK + q * 8);
    #pragma unroll
    for (int ni = 0; ni < 4; ++ni)
      bfr[ni] = *(const bf16x8*)(Bc + (wc + ni * 16 + lr) * BK + q * 8);
    rv = *slots_ready;                  // pipelined ready-check for iter j+1
    #pragma unroll
    for (int mi = 0; mi < 4; ++mi)
      #pragma unroll
      for (int ni = 0; ni < 4; ++ni)
        acc[mi][ni] = __builtin_amdgcn_mfma_f32_16x16x32_bf16(
            af[mi], bfr[ni], acc[mi][ni], 0, 0, 0);
    __asm__ volatile("" ::: "memory");  // ds_reads pinned above the release
    if (lane == 0) atomicAdd(&done[slot], 1);
  }
}

// ---------------- generic GEMM ----------------
// mode: 0 = bf16 row-major, 2 = f32 row-major,
//       3 = bf16 transposed-packed: store C^T (Cb[col*ldC + row]), 8B packed.
__global__ __launch_bounds__(320) void gemm_bt(
    const __hip_bfloat16* __restrict__ A,
    const __hip_bfloat16* __restrict__ B,
    void* __restrict__ Cv,
    const float* __restrict__ bias,
    int K, int ldC,
    long sA, long sB, long sC,
    float scale, int mode)
{
  __shared__ __hip_bfloat16 As[NSLOT][SLOT_E];
  __shared__ __hip_bfloat16 Bs[NSLOT][SLOT_E];
  __shared__ int slots_ready;
  __shared__ int done[NSLOT];

  const long z = blockIdx.z;
  const int tid  = threadIdx.x;
  const int lane = tid & 63;
  const int wid  = tid >> 6;            // 0..3 consumers, 4 producer
  const long rowBase = (long)blockIdx.x * 128;
  const long colBase = (long)blockIdx.y * 128;

  if (tid == 0) { slots_ready = 0; done[0] = 0; done[1] = 0; done[2] = 0; }
  __syncthreads();   // the only barrier; nothing in flight

  if (wid == 4) {
    producer_loop(A + z * sA, B + z * sB, As, Bs, &slots_ready, done,
                  rowBase, colBase, K, lane);
    return;
  }

  const int wr = (wid >> 1) * 64;
  const int wc = (wid & 1) * 64;
  const int lr = lane & 15;
  const int q  = lane >> 4;
  f32x4 acc[4][4] = {};
  consumer_loop(As, Bs, &slots_ready, done, K, wr, wc, lr, q, lane, acc);

  if (mode == 3) {
    __hip_bfloat16* Cb = (__hip_bfloat16*)Cv + z * sC;
    #pragma unroll
    for (int ni = 0; ni < 4; ++ni) {
      long col = colBase + wc + ni * 16 + lr;
      #pragma unroll
      for (int mi = 0; mi < 4; ++mi) {
        long row = rowBase + wr + mi * 16 + q * 4;
        s16x4 pk = { bfpack(acc[mi][ni][0] * scale), bfpack(acc[mi][ni][1] * scale),
                     bfpack(acc[mi][ni][2] * scale), bfpack(acc[mi][ni][3] * scale) };
        *(s16x4*)(Cb + col * (long)ldC + row) = pk;
      }
    }
    return;
  }

  #pragma unroll
  for (int ni = 0; ni < 4; ++ni) {
    long col = colBase + wc + ni * 16 + lr;
    float bv = bias ? bias[col] : 0.0f;
    #pragma unroll
    for (int mi = 0; mi < 4; ++mi) {
      #pragma unroll
      for (int i = 0; i < 4; ++i) {
        long row = rowBase + wr + mi * 16 + q * 4 + i;
        float v = acc[mi][ni][i] * scale + bv;
        if (mode == 0)
          ((__hip_bfloat16*)Cv)[z * sC + row * (long)ldC + col] = __float2bfloat16(v);
        else
          ((float*)Cv)[z * sC + row * (long)ldC + col] = v;
      }
    }
  }
}

// ---------------- fused QKV projection (V-slot carries Wvo) ----------------
// A = xb[8192,1024], B = Wqkvb[3072,1024] (Wq | Wk | Wvo). Col group (block-
// uniform): 0 -> Q (+bq), 1 -> K (+bk), 2 -> VWo^T[4][1024][2048] packed 8B.
__global__ __launch_bounds__(320) void gemm_qkv(
    const __hip_bfloat16* __restrict__ A,
    const __hip_bfloat16* __restrict__ B,
    __hip_bfloat16* __restrict__ Q,
    __hip_bfloat16* __restrict__ Kd,
    __hip_bfloat16* __restrict__ Vt,
    const float* __restrict__ bq,
    const float* __restrict__ bk)
{
  __shared__ __hip_bfloat16 As[NSLOT][SLOT_E];
  __shared__ __hip_bfloat16 Bs[NSLOT][SLOT_E];
  __shared__ int slots_ready;
  __shared__ int done[NSLOT];

  const int tid  = threadIdx.x;
  const int lane = tid & 63;
  const int wid  = tid >> 6;
  const long rowBase = (long)blockIdx.x * 128;
  const long colBase = (long)blockIdx.y * 128;

  if (tid == 0) { slots_ready = 0; done[0] = 0; done[1] = 0; done[2] = 0; }
  __syncthreads();

  if (wid == 4) {
    producer_loop(A, B, As, Bs, &slots_ready, done, rowBase, colBase, 1024, lane);
    return;
  }

  const int wr = (wid >> 1) * 64;
  const int wc = (wid & 1) * 64;
  const int lr = lane & 15;
  const int q  = lane >> 4;
  f32x4 acc[4][4] = {};
  consumer_loop(As, Bs, &slots_ready, done, 1024, wr, wc, lr, q, lane, acc);

  const int cg = (int)(colBase >> 10);  // 0=Q, 1=K, 2=VWo (block-uniform)

  if (cg == 2) {
    #pragma unroll
    for (int ni = 0; ni < 4; ++ni) {
      long colL = (colBase + wc + ni * 16 + lr) & 1023;
      #pragma unroll
      for (int mi = 0; mi < 4; ++mi) {
        long row0 = rowBase + wr + mi * 16 + q * 4;   // 4 rows, same batch
        long b = row0 >> 11, s = row0 & 2047;
        s16x4 pk = { bfpack(acc[mi][ni][0]), bfpack(acc[mi][ni][1]),
                     bfpack(acc[mi][ni][2]), bfpack(acc[mi][ni][3]) };
        *(s16x4*)(Vt + b * (1024L * 2048L) + colL * 2048L + s) = pk;
      }
    }
    return;
  }

  __hip_bfloat16* Dst = (cg == 0) ? Q : Kd;
  const float* bias = (cg == 0) ? bq : bk;
  #pragma unroll
  for (int ni = 0; ni < 4; ++ni) {
    long colL = (colBase + wc + ni * 16 + lr) & 1023;
    float bvv = bias[colL];
    #pragma unroll
    for (int mi = 0; mi < 4; ++mi) {
      #pragma unroll
      for (int i = 0; i < 4; ++i) {
        long row = rowBase + wr + mi * 16 + q * 4 + i;
        Dst[row * 1024 + colL] = __float2bfloat16(acc[mi][ni][i] + bvv);
      }
    }
  }
}

// f32 -> bf16 conversion, 8 elems/thread.
__global__ __launch_bounds__(256) void cvt_f32_bf16(
    const float* __restrict__ in, __hip_bfloat16* __restrict__ out)
{
  long i = ((long)blockIdx.x * 256 + threadIdx.x) * 8;
  float4 a = *(const float4*)(in + i);
  float4 b = *(const float4*)(in + i + 4);
  bf16x8 o;
  o[0] = bfpack(a.x); o[1] = bfpack(a.y); o[2] = bfpack(a.z); o[3] = bfpack(a.w);
  o[4] = bfpack(b.x); o[5] = bfpack(b.y); o[6] = bfpack(b.z); o[7] = bfpack(b.w);
  *(bf16x8*)(out + i) = o;
}

// Transpose-convert: in f32 [1024][1024] -> out bf16 transposed. 64x64 LDS tiles.
__global__ __launch_bounds__(256) void cvt_t_f32_bf16(
    const float* __restrict__ in, __hip_bfloat16* __restrict__ out)
{
  __shared__ __hip_bfloat16 t[64][65];
  const int tid = threadIdx.x;
  const long rb = (long)blockIdx.y * 64;
  const long cb = (long)blockIdx.x * 64;
  const int r0 = tid >> 4;
  const int c0 = (tid & 15) * 4;
  #pragma unroll
  for (int p = 0; p < 4; ++p) {
    int r = r0 + p * 16;
    float4 v = *(const float4*)(in + (rb + r) * 1024 + cb + c0);
    t[c0 + 0][r] = __float2bfloat16(v.x);
    t[c0 + 1][r] = __float2bfloat16(v.y);
    t[c0 + 2][r] = __float2bfloat16(v.z);
    t[c0 + 3][r] = __float2bfloat16(v.w);
  }
  __syncthreads();
  #pragma unroll
  for (int p = 0; p < 4; ++p) {
    int r = r0 + p * 16;
    __hip_bfloat16* o = out + (cb + r) * 1024 + rb + c0;
    o[0] = t[r][c0 + 0]; o[1] = t[r][c0 + 1];
    o[2] = t[r][c0 + 2]; o[3] = t[r][c0 + 3];
  }
}

// bfinal[e] = dot(Wo[e,:], bv) + bo[e]  (f32)
__global__ __launch_bounds__(256) void bias_vo(
    const float* __restrict__ Wo, const float* __restrict__ bv,
    const float* __restrict__ bo, float* __restrict__ bfinal)
{
  int e = blockIdx.x * 4 + (threadIdx.x >> 6);
  int lane = threadIdx.x & 63;
  const float* row = Wo + (long)e * 1024;
  float s = 0.0f;
  #pragma unroll
  for (int p = 0; p < 4; ++p) {
    float4 w = *(const float4*)(row + p * 256 + lane * 4);
    float4 b = *(const float4*)(bv + p * 256 + lane * 4);
    s += w.x * b.x + w.y * b.y + w.z * b.z + w.w * b.w;
  }
  #pragma unroll
  for (int o = 32; o; o >>= 1) s += __shfl_xor(s, o);
  if (lane == 0) bfinal[e] = s + bo[e];
}

// In-place row softmax over 2048 bf16 elements. One 256-thread block per row.
__global__ __launch_bounds__(256) void softmax_rows(__hip_bfloat16* __restrict__ P)
{
  const int tid  = threadIdx.x;
  const int lane = tid & 63;
  const int wid  = tid >> 6;
  __hip_bfloat16* p = P + (long)blockIdx.x * 2048 + tid * 8;

  bf16x8 v = *(const bf16x8*)p;
  float x[8];
  #pragma unroll
  for (int i = 0; i < 8; ++i)
    x[i] = __uint_as_float(((unsigned)(unsigned short)v[i]) << 16);

  float m = x[0];
  #pragma unroll
  for (int i = 1; i < 8; ++i) m = fmaxf(m, x[i]);
  #pragma unroll
  for (int o = 32; o; o >>= 1) m = fmaxf(m, __shfl_xor(m, o));

  __shared__ float rmax[4], rsum[4];
  if (lane == 0) rmax[wid] = m;
  __syncthreads();
  m = fmaxf(fmaxf(rmax[0], rmax[1]), fmaxf(rmax[2], rmax[3]));

  float e[8], s = 0.0f;
  #pragma unroll
  for (int i = 0; i < 8; ++i) { e[i] = __expf(x[i] - m); s += e[i]; }
  #pragma unroll
  for (int o = 32; o; o >>= 1) s += __shfl_xor(s, o);
  if (lane == 0) rsum[wid] = s;
  __syncthreads();
  s = (rsum[0] + rsum[1]) + (rsum[2] + rsum[3]);

  float inv = 1.0f / s;
  bf16x8 ov;
  #pragma unroll
  for (int i = 0; i < 8; ++i) ov[i] = bfpack(e[i] * inv);
  *(bf16x8*)p = ov;
}

extern "C" void kernel_launch(void* const* d_in, const int* in_sizes, int n_in,
                              void* d_out, int out_size, void* d_ws, size_t ws_size,
                              hipStream_t stream) {
  const float* x  = (const float*)d_in[0];
  const float* Wq = (const float*)d_in[1];
  const float* bq = (const float*)d_in[2];
  const float* Wk = (const float*)d_in[3];
  const float* bk = (const float*)d_in[4];
  const float* Wv = (const float*)d_in[5];
  const float* bv = (const float*)d_in[6];
  const float* Wo = (const float*)d_in[7];
  const float* bo = (const float*)d_in[8];
  float* out = (float*)d_out;

  const long B = 4, S = 2048, D = 1024;
  char* ws = (char*)d_ws;
  __hip_bfloat16* xb    = (__hip_bfloat16*)ws; ws += B * S * D * 2;  // 16.8 MB
  __hip_bfloat16* Wqkvb = (__hip_bfloat16*)ws; ws += 3 * D * D * 2;  //  6.3 MB (Wq|Wk|Wvo)
  __hip_bfloat16* Wob   = (__hip_bfloat16*)ws; ws += D * D * 2;      //  2.1 MB
  __hip_bfloat16* Q     = (__hip_bfloat16*)ws; ws += B * S * D * 2;  // 16.8 MB
  __hip_bfloat16* Km    = (__hip_bfloat16*)ws; ws += B * S * D * 2;  // 16.8 MB
  __hip_bfloat16* VWot  = (__hip_bfloat16*)ws; ws += B * D * S * 2;  // 16.8 MB [B][D][S]
  __hip_bfloat16* P     = (__hip_bfloat16*)ws; ws += B * S * S * 2;  // 33.5 MB
  __hip_bfloat16* Wvtb   = Q;            // Wv^T bf16, dead before gemm_qkv writes Q
  float*          bfinal = (float*)Wob;  // overwrites Wob AFTER the Wvo GEMM reads it

  dim3 blk(256), blkg(320);
  // converts
  cvt_f32_bf16<<<dim3(4096), blk, 0, stream>>>(x,  xb);
  cvt_f32_bf16<<<dim3(512),  blk, 0, stream>>>(Wq, Wqkvb);
  cvt_f32_bf16<<<dim3(512),  blk, 0, stream>>>(Wk, Wqkvb + D * D);
  cvt_f32_bf16<<<dim3(512),  blk, 0, stream>>>(Wo, Wob);
  cvt_t_f32_bf16<<<dim3(16, 16), blk, 0, stream>>>(Wv, Wvtb);

  // Wvo = Wo · Wv (via Wv^T) -> QKV weight slot 2
  gemm_bt<<<dim3(8, 8, 1), blkg, 0, stream>>>(Wob, Wvtb, Wqkvb + 2 * D * D,
                                              nullptr, 1024, 1024, 0, 0, 0, 1.0f, 0);
  // bfinal = Wo·bv + bo (overwrites Wob region, safe after Wvo GEMM)
  bias_vo<<<dim3(256), blk, 0, stream>>>(Wo, bv, bo, bfinal);

  // fused QKV projection: M=8192, N=3072, K=1024 -> Q, K, VWo^T
  gemm_qkv<<<dim3(64, 24, 1), blkg, 0, stream>>>(xb, Wqkvb, Q, Km, VWot, bq, bk);
  // scores^T orientation: A=K, B=Q, mode 3 stores P[q][k] packed 8B.
  gemm_bt<<<dim3(16, 16, 4), blkg, 0, stream>>>(Km, Q, P, nullptr, 1024, 2048,
                                                S * D, S * D, S * S, 0.125f, 3);
  // softmax over each of 4*2048 rows
  softmax_rows<<<dim3(8192), blk, 0, stream>>>(P);
  // out = P · VWo + bfinal (f32): M=2048, N=1024, K=2048, batched
  gemm_bt<<<dim3(16, 8, 4), blkg, 0, stream>>>(P, VWot, out, bfinal, 2048, 1024,
                                               S * S, D * S, S * D, 1.0f, 2);
}